// Round 1
// baseline (804.190 us; speedup 1.0000x reference)
//
#include <hip/hip_runtime.h>
#include <hip/hip_bf16.h>
#include <stdint.h>

#define N_NODES 50000
#define N_PAD   50048   // 391 * 128
#define E_EDGES 800000
#define MT      391     // row tiles of 128

typedef __bf16 bf16x8 __attribute__((ext_vector_type(8)));
typedef float  f32x4  __attribute__((ext_vector_type(4)));

// ---------------- CSR build ----------------
__global__ void count_deg(const int* __restrict__ ei, int* __restrict__ cnt) {
    int e = blockIdx.x * blockDim.x + threadIdx.x;
    if (e < E_EDGES) atomicAdd(&cnt[ei[E_EDGES + e]], 1);
}

__global__ void scan_excl(const int* __restrict__ cnt, int* __restrict__ ptr, int n) {
    __shared__ int buf[1024];
    __shared__ int carry;
    if (threadIdx.x == 0) carry = 0;
    __syncthreads();
    for (int base = 0; base < n; base += 1024) {
        int i = base + (int)threadIdx.x;
        int v = (i < n) ? cnt[i] : 0;
        buf[threadIdx.x] = v;
        __syncthreads();
        #pragma unroll
        for (int off = 1; off < 1024; off <<= 1) {
            int t = (threadIdx.x >= (unsigned)off) ? buf[threadIdx.x - off] : 0;
            __syncthreads();
            buf[threadIdx.x] += t;
            __syncthreads();
        }
        if (i < n) ptr[i] = carry + buf[threadIdx.x] - v;   // exclusive
        int total = buf[1023];
        __syncthreads();
        if (threadIdx.x == 0) carry += total;
        __syncthreads();
    }
    if (threadIdx.x == 0) ptr[n] = carry;
}

__global__ void fill_csr(const int* __restrict__ ei, const int* __restrict__ ptr,
                         int* __restrict__ cursor, int* __restrict__ col) {
    int e = blockIdx.x * blockDim.x + threadIdx.x;
    if (e < E_EDGES) {
        int dst = ei[E_EDGES + e];
        int pos = ptr[dst] + atomicAdd(&cursor[dst], 1);
        col[pos] = ei[e];
    }
}

// ---------------- fp32 -> bf16 weight convert ----------------
__global__ void f2b(const float* __restrict__ s, __bf16* __restrict__ d, int n) {
    int i = blockIdx.x * blockDim.x + threadIdx.x;
    if (i < n) d[i] = (__bf16)s[i];
}

// ---------------- aggregation (gather over CSR) ----------------
// agg0 = x + sum_{j in N(i)} x_j  (64-dim, fp32 accumulate, bf16 out). wave per node.
__global__ void agg0_gather(const float* __restrict__ x, const int* __restrict__ ptr,
                            const int* __restrict__ col, __bf16* __restrict__ out) {
    int node = blockIdx.x * 4 + (threadIdx.x >> 6);
    int lane = threadIdx.x & 63;
    if (node >= N_PAD) return;
    long o = (long)node * 64 + lane;
    if (node >= N_NODES) { out[o] = (__bf16)0.0f; return; }
    float acc = x[o];
    int e0 = ptr[node], e1 = ptr[node + 1];
    for (int e = e0; e < e1; ++e) acc += x[(long)col[e] * 64 + lane];
    out[o] = (__bf16)acc;
}

// agg over projected t (256-dim fp32), fused bias + relu + bf16 out. block(256) per node.
__global__ void aggt_gather(const float* __restrict__ t, const int* __restrict__ ptr,
                            const int* __restrict__ col, const float* __restrict__ b_m1,
                            const float* __restrict__ b_l1, __bf16* __restrict__ p) {
    int node = blockIdx.x;
    int f = threadIdx.x;
    float acc = t[(long)node * 256 + f];
    int e0 = ptr[node], e1 = ptr[node + 1];
    for (int e = e0; e < e1; ++e) acc += t[(long)col[e] * 256 + f];
    acc += (f < 128) ? b_m1[f] : b_l1[f - 128];
    acc = fmaxf(acc, 0.0f);
    p[(long)node * 256 + f] = (__bf16)acc;
}

// ---------------- bf16 MFMA GEMM: C[M,N] = A[M,K] * W[N,K]^T (+bias, act) ----------------
__device__ __forceinline__ void gl_lds16(const __bf16* g, __bf16* l) {
    __builtin_amdgcn_global_load_lds(
        (const __attribute__((address_space(1))) uint32_t*)g,
        (__attribute__((address_space(3))) uint32_t*)l, 16, 0, 0);
}

// ACT: 0 none, 1 leaky_relu(0.1), 2 relu
template <int ACT, bool BIAS, bool OUT_BF16>
__global__ __launch_bounds__(256) void gemm_bt(
    const __bf16* __restrict__ A, int lda, const __bf16* __restrict__ W,
    const float* __restrict__ bias, void* __restrict__ Cout, int ldc,
    int K, int Mstore) {
    // LDS tile layout [128 rows][32 k] with per-row XOR swizzle of the 8-elem k-group:
    // element (r,k) lives at r*32 + (( (k>>3) ^ ((r>>1)&3) )<<3) + (k&7)
    __shared__ __bf16 As[128 * 32];
    __shared__ __bf16 Ws[128 * 32];

    const int tid  = threadIdx.x;
    const int wid  = tid >> 6;
    const int lane = tid & 63;
    const long blockRow = (long)blockIdx.x * 128;
    const int  blockCol = blockIdx.y * 128;
    const int wm = (wid >> 1) << 6;   // wave's 64-row slab
    const int wn = (wid & 1) << 6;    // wave's 64-col slab

    f32x4 acc[4][4];
    #pragma unroll
    for (int i = 0; i < 4; ++i)
        #pragma unroll
        for (int j = 0; j < 4; ++j) acc[i][j] = (f32x4)0.0f;

    // staging: each wave fills 2 chunks of 16 rows (1KB each), lane -> base + lane*16
    const int c0 = wid * 2;
    const int lr = lane >> 2;                               // row within 16-row chunk
    const int kg = (lane & 3) ^ ((lane >> 3) & 3);          // swizzled k-group
    const __bf16* gA0 = A + (blockRow + c0 * 16 + lr) * (long)lda + kg * 8;
    const __bf16* gA1 = gA0 + 16L * lda;
    const __bf16* gW0 = W + ((long)blockCol + c0 * 16 + lr) * (long)K + kg * 8;
    const __bf16* gW1 = gW0 + 16L * K;
    __bf16* lA0 = As + c0 * 512;
    __bf16* lA1 = lA0 + 512;
    __bf16* lW0 = Ws + c0 * 512;
    __bf16* lW1 = lW0 + 512;

    const int rA  = lane & 15;
    const int q   = lane >> 4;
    const int swz = ((q ^ ((rA >> 1) & 3)) << 3);

    for (int k0 = 0; k0 < K; k0 += 32) {
        gl_lds16(gA0 + k0, lA0);
        gl_lds16(gA1 + k0, lA1);
        gl_lds16(gW0 + k0, lW0);
        gl_lds16(gW1 + k0, lW1);
        __syncthreads();   // waits vmcnt(0): global_load_lds landed

        bf16x8 af[4], bf[4];
        #pragma unroll
        for (int mi = 0; mi < 4; ++mi)
            af[mi] = *(const bf16x8*)&As[(wm + mi * 16 + rA) * 32 + swz];
        #pragma unroll
        for (int ni = 0; ni < 4; ++ni)
            bf[ni] = *(const bf16x8*)&Ws[(wn + ni * 16 + rA) * 32 + swz];
        #pragma unroll
        for (int mi = 0; mi < 4; ++mi)
            #pragma unroll
            for (int ni = 0; ni < 4; ++ni)
                acc[mi][ni] = __builtin_amdgcn_mfma_f32_16x16x32_bf16(
                    af[mi], bf[ni], acc[mi][ni], 0, 0, 0);
        __syncthreads();   // protect LDS before next stage
    }

    // epilogue: C/D layout col=lane&15, row=(lane>>4)*4+reg
    const int ccol = lane & 15;
    const int crow = (lane >> 4) << 2;
    #pragma unroll
    for (int mi = 0; mi < 4; ++mi) {
        #pragma unroll
        for (int ni = 0; ni < 4; ++ni) {
            long gr0 = blockRow + wm + mi * 16 + crow;
            int  gc  = blockCol + wn + ni * 16 + ccol;
            float bv = BIAS ? bias[gc] : 0.0f;
            #pragma unroll
            for (int r = 0; r < 4; ++r) {
                long gr = gr0 + r;
                if (gr < Mstore) {
                    float v = acc[mi][ni][r] + bv;
                    if (ACT == 1) v = (v > 0.0f) ? v : 0.1f * v;
                    else if (ACT == 2) v = fmaxf(v, 0.0f);
                    if (OUT_BF16) ((__bf16*)Cout)[gr * ldc + gc] = (__bf16)v;
                    else          ((float*)Cout)[gr * ldc + gc] = v;
                }
            }
        }
    }
}

extern "C" void kernel_launch(void* const* d_in, const int* in_sizes, int n_in,
                              void* d_out, int out_size, void* d_ws, size_t ws_size,
                              hipStream_t stream) {
    const float* x    = (const float*)d_in[0];
    const int*   ei   = (const int*)d_in[1];      // [2][E], int per harness contract
    const float* W_s1 = (const float*)d_in[2];
    const float* b_s1 = (const float*)d_in[3];
    const float* W_s2 = (const float*)d_in[4];
    const float* b_s2 = (const float*)d_in[5];
    const float* W_s3 = (const float*)d_in[6];
    const float* b_s3 = (const float*)d_in[7];
    const float* W_s4 = (const float*)d_in[8];
    const float* b_s4 = (const float*)d_in[9];
    const float* W_m1 = (const float*)d_in[10];
    const float* b_m1 = (const float*)d_in[11];
    const float* W_m2 = (const float*)d_in[12];
    const float* b_m2 = (const float*)d_in[13];
    const float* W_l1 = (const float*)d_in[14];
    const float* b_l1 = (const float*)d_in[15];
    const float* W_l2 = (const float*)d_in[16];
    const float* b_l2 = (const float*)d_in[17];

    char* ws = (char*)d_ws;
    size_t off = 0;
    auto carve = [&](size_t bytes) -> void* {
        void* p = ws + off;
        off = (off + bytes + 255) & ~(size_t)255;
        return p;
    };
    int* cnt = (int*)carve((size_t)N_NODES * 4);
    int* cur = (int*)carve((size_t)N_NODES * 4);
    int* ptr = (int*)carve((size_t)(N_NODES + 1) * 4);
    int* col = (int*)carve((size_t)E_EDGES * 4);
    __bf16* w1  = (__bf16*)carve((size_t)512 * 64 * 2);
    __bf16* w2  = (__bf16*)carve((size_t)512 * 512 * 2);
    __bf16* w3  = (__bf16*)carve((size_t)512 * 512 * 2);
    __bf16* w4  = (__bf16*)carve((size_t)512 * 512 * 2);
    __bf16* wml = (__bf16*)carve((size_t)256 * 512 * 2);  // [W_m1; W_l1]
    __bf16* wm2 = (__bf16*)carve((size_t)128 * 128 * 2);
    __bf16* wl2 = (__bf16*)carve((size_t)128 * 128 * 2);
    __bf16* agg0b = (__bf16*)carve((size_t)N_PAD * 64 * 2);
    __bf16* B1    = (__bf16*)carve((size_t)N_PAD * 512 * 2);
    __bf16* B2    = (__bf16*)carve((size_t)N_PAD * 512 * 2);

    (void)hipMemsetAsync(cnt, 0, (size_t)N_NODES * 4, stream);
    (void)hipMemsetAsync(cur, 0, (size_t)N_NODES * 4, stream);
    count_deg<<<E_EDGES / 256, 256, 0, stream>>>(ei, cnt);
    scan_excl<<<1, 1024, 0, stream>>>(cnt, ptr, N_NODES);
    fill_csr<<<E_EDGES / 256, 256, 0, stream>>>(ei, ptr, cur, col);

    f2b<<<(512 * 64 + 255) / 256, 256, 0, stream>>>(W_s1, w1, 512 * 64);
    f2b<<<(512 * 512 + 255) / 256, 256, 0, stream>>>(W_s2, w2, 512 * 512);
    f2b<<<(512 * 512 + 255) / 256, 256, 0, stream>>>(W_s3, w3, 512 * 512);
    f2b<<<(512 * 512 + 255) / 256, 256, 0, stream>>>(W_s4, w4, 512 * 512);
    f2b<<<(128 * 512 + 255) / 256, 256, 0, stream>>>(W_m1, wml, 128 * 512);
    f2b<<<(128 * 512 + 255) / 256, 256, 0, stream>>>(W_l1, wml + 128 * 512, 128 * 512);
    f2b<<<(128 * 128 + 255) / 256, 256, 0, stream>>>(W_m2, wm2, 128 * 128);
    f2b<<<(128 * 128 + 255) / 256, 256, 0, stream>>>(W_l2, wl2, 128 * 128);

    agg0_gather<<<N_PAD / 4, 256, 0, stream>>>(x, ptr, col, agg0b);

    // shared MLP: 64->512->512->512->512, lrelu x3, final +b then relu
    gemm_bt<1, true, true><<<dim3(MT, 4), 256, 0, stream>>>(agg0b, 64, w1, b_s1, B1, 512, 64, N_PAD);
    gemm_bt<1, true, true><<<dim3(MT, 4), 256, 0, stream>>>(B1, 512, w2, b_s2, B2, 512, 512, N_PAD);
    gemm_bt<1, true, true><<<dim3(MT, 4), 256, 0, stream>>>(B2, 512, w3, b_s3, B1, 512, 512, N_PAD);
    gemm_bt<2, true, true><<<dim3(MT, 4), 256, 0, stream>>>(B1, 512, w4, b_s4, B2, 512, 512, N_PAD);

    // project h -> 256 (mu|logvar heads) BEFORE aggregation (segment_sum commutes with linear)
    float* t = (float*)B1;  // N_PAD x 256 fp32, reuses B1 bytes exactly
    gemm_bt<0, false, false><<<dim3(MT, 2), 256, 0, stream>>>(B2, 512, wml, nullptr, t, 256, 512, N_PAD);

    __bf16* p = B2;  // N x 256 bf16 (relu(agg + bias))
    aggt_gather<<<N_NODES, 256, 0, stream>>>(t, ptr, col, b_m1, b_l1, p);

    float* mu = (float*)d_out;
    float* lv = mu + (size_t)N_NODES * 128;
    gemm_bt<0, true, false><<<dim3(MT, 1), 256, 0, stream>>>(p, 256, wm2, b_m2, mu, 128, 128, N_NODES);
    gemm_bt<0, true, false><<<dim3(MT, 1), 256, 0, stream>>>(p + 128, 256, wl2, b_l2, lv, 128, 128, N_NODES);
}

// Round 2
// 520.322 us; speedup vs baseline: 1.5456x; 1.5456x over previous
//
#include <hip/hip_runtime.h>
#include <hip/hip_bf16.h>
#include <stdint.h>

#define N_NODES 50000
#define N_PAD   50048   // 391 * 128
#define E_EDGES 800000
#define MT      391     // row tiles of 128

typedef __bf16 bf16x8 __attribute__((ext_vector_type(8)));
typedef __bf16 bf16x4 __attribute__((ext_vector_type(4)));
typedef float  f32x4  __attribute__((ext_vector_type(4)));

// ---------------- CSR build ----------------
__global__ void count_deg(const int* __restrict__ ei, int* __restrict__ cnt) {
    int e = blockIdx.x * blockDim.x + threadIdx.x;
    if (e < E_EDGES) atomicAdd(&cnt[ei[E_EDGES + e]], 1);
}

// multi-block exclusive scan: phase 1 (block-local) -----------------------------
#define SCAN_B 1024
__global__ void scan_block(const int* __restrict__ cnt, int* __restrict__ ptr,
                           int* __restrict__ bsum, int n) {
    __shared__ int buf[SCAN_B];
    int i = blockIdx.x * SCAN_B + threadIdx.x;
    int v = (i < n) ? cnt[i] : 0;
    buf[threadIdx.x] = v;
    __syncthreads();
    #pragma unroll
    for (int off = 1; off < SCAN_B; off <<= 1) {
        int t = (threadIdx.x >= (unsigned)off) ? buf[threadIdx.x - off] : 0;
        __syncthreads();
        buf[threadIdx.x] += t;
        __syncthreads();
    }
    if (i < n) ptr[i] = buf[threadIdx.x] - v;            // block-local exclusive
    if (threadIdx.x == SCAN_B - 1) bsum[blockIdx.x] = buf[SCAN_B - 1];
}

// phase 2: scan the <=64 block sums in one 64-thread block ----------------------
__global__ void scan_bsums(int* __restrict__ bsum, int* __restrict__ boff, int nb,
                           int* __restrict__ total_out) {
    __shared__ int buf[64];
    int v = ((int)threadIdx.x < nb) ? bsum[threadIdx.x] : 0;
    buf[threadIdx.x] = v;
    __syncthreads();
    #pragma unroll
    for (int off = 1; off < 64; off <<= 1) {
        int t = (threadIdx.x >= (unsigned)off) ? buf[threadIdx.x - off] : 0;
        __syncthreads();
        buf[threadIdx.x] += t;
        __syncthreads();
    }
    if ((int)threadIdx.x < nb) boff[threadIdx.x] = buf[threadIdx.x] - v;
    if (threadIdx.x == 63) *total_out = buf[63];         // == E, -> ptr[N]
}

// phase 3: add block offsets ----------------------------------------------------
__global__ void scan_add(int* __restrict__ ptr, const int* __restrict__ boff, int n) {
    int i = blockIdx.x * SCAN_B + threadIdx.x;
    if (i < n) ptr[i] += boff[blockIdx.x];
}

__global__ void fill_csr(const int* __restrict__ ei, const int* __restrict__ ptr,
                         int* __restrict__ cursor, int* __restrict__ col) {
    int e = blockIdx.x * blockDim.x + threadIdx.x;
    if (e < E_EDGES) {
        int dst = ei[E_EDGES + e];
        int pos = ptr[dst] + atomicAdd(&cursor[dst], 1);
        col[pos] = ei[e];
    }
}

// ---------------- one-shot fp32 -> bf16 conversion (x + all weights) -----------
// wbuf layout (bf16 elems): w1[32768] w2[262144] w3[262144] w4[262144]
//                           wm1[65536] wl1[65536] wm2[16384] wl2[16384]
#define XN      3200000
#define WTOT    983040
__global__ void cvt_all(const float* __restrict__ x,
                        const float* __restrict__ Ws1, const float* __restrict__ Ws2,
                        const float* __restrict__ Ws3, const float* __restrict__ Ws4,
                        const float* __restrict__ Wm1, const float* __restrict__ Wl1,
                        const float* __restrict__ Wm2, const float* __restrict__ Wl2,
                        __bf16* __restrict__ xb, __bf16* __restrict__ wbuf) {
    int i = blockIdx.x * blockDim.x + threadIdx.x;
    if (i < XN) { xb[i] = (__bf16)x[i]; return; }
    int j = i - XN;
    if (j >= WTOT) return;
    const float* s; int o;
    if      (j <  32768) { s = Ws1; o = j; }
    else if (j < 294912) { s = Ws2; o = j -  32768; }
    else if (j < 557056) { s = Ws3; o = j - 294912; }
    else if (j < 819200) { s = Ws4; o = j - 557056; }
    else if (j < 884736) { s = Wm1; o = j - 819200; }
    else if (j < 950272) { s = Wl1; o = j - 884736; }
    else if (j < 966656) { s = Wm2; o = j - 950272; }
    else                 { s = Wl2; o = j - 966656; }
    wbuf[j] = (__bf16)s[o];
}

// ---------------- aggregation (gather over CSR, fp32 accumulate) ---------------
// agg0 = x + sum_{j in N(i)} x_j  (64-dim bf16 in, bf16 out). wave per node.
__global__ void agg0_gather(const __bf16* __restrict__ xb, const int* __restrict__ ptr,
                            const int* __restrict__ col, __bf16* __restrict__ out) {
    int node = blockIdx.x * 4 + (threadIdx.x >> 6);
    int lane = threadIdx.x & 63;
    if (node >= N_PAD) return;
    long o = (long)node * 64 + lane;
    if (node >= N_NODES) { out[o] = (__bf16)0.0f; return; }
    float acc = (float)xb[o];
    int e0 = ptr[node], e1 = ptr[node + 1];
    int e = e0;
    for (; e + 4 <= e1; e += 4) {               // 4 independent loads in flight
        int c0 = col[e], c1 = col[e + 1], c2 = col[e + 2], c3 = col[e + 3];
        float v0 = (float)xb[(long)c0 * 64 + lane];
        float v1 = (float)xb[(long)c1 * 64 + lane];
        float v2 = (float)xb[(long)c2 * 64 + lane];
        float v3 = (float)xb[(long)c3 * 64 + lane];
        acc += (v0 + v1) + (v2 + v3);
    }
    for (; e < e1; ++e) acc += (float)xb[(long)col[e] * 64 + lane];
    out[o] = (__bf16)acc;
}

// agg over projected t (256-dim bf16), fused bias + relu, bf16 out. wave per node,
// lane covers dims 4*lane..4*lane+3 via 8-B vector loads; edge loop unrolled x4.
__global__ void aggt_gather(const __bf16* __restrict__ t, const int* __restrict__ ptr,
                            const int* __restrict__ col, const float* __restrict__ b_m1,
                            const float* __restrict__ b_l1, __bf16* __restrict__ p) {
    int node = blockIdx.x * 4 + (threadIdx.x >> 6);
    int lane = threadIdx.x & 63;
    if (node >= N_NODES) return;
    const int f0 = lane * 4;
    bf16x4 s = *(const bf16x4*)&t[(long)node * 256 + f0];
    float a0 = (float)s[0], a1 = (float)s[1], a2 = (float)s[2], a3 = (float)s[3];
    int e0 = ptr[node], e1 = ptr[node + 1];
    int e = e0;
    for (; e + 4 <= e1; e += 4) {               // 4 independent 8-B loads in flight
        int c0 = col[e], c1 = col[e + 1], c2 = col[e + 2], c3 = col[e + 3];
        bf16x4 v0 = *(const bf16x4*)&t[(long)c0 * 256 + f0];
        bf16x4 v1 = *(const bf16x4*)&t[(long)c1 * 256 + f0];
        bf16x4 v2 = *(const bf16x4*)&t[(long)c2 * 256 + f0];
        bf16x4 v3 = *(const bf16x4*)&t[(long)c3 * 256 + f0];
        a0 += ((float)v0[0] + (float)v1[0]) + ((float)v2[0] + (float)v3[0]);
        a1 += ((float)v0[1] + (float)v1[1]) + ((float)v2[1] + (float)v3[1]);
        a2 += ((float)v0[2] + (float)v1[2]) + ((float)v2[2] + (float)v3[2]);
        a3 += ((float)v0[3] + (float)v1[3]) + ((float)v2[3] + (float)v3[3]);
    }
    for (; e < e1; ++e) {
        bf16x4 v = *(const bf16x4*)&t[(long)col[e] * 256 + f0];
        a0 += (float)v[0]; a1 += (float)v[1]; a2 += (float)v[2]; a3 += (float)v[3];
    }
    float b0, b1, b2, b3;
    if (f0 < 128) { b0 = b_m1[f0]; b1 = b_m1[f0+1]; b2 = b_m1[f0+2]; b3 = b_m1[f0+3]; }
    else          { b0 = b_l1[f0-128]; b1 = b_l1[f0-127]; b2 = b_l1[f0-126]; b3 = b_l1[f0-125]; }
    bf16x4 r;
    r[0] = (__bf16)fmaxf(a0 + b0, 0.0f);
    r[1] = (__bf16)fmaxf(a1 + b1, 0.0f);
    r[2] = (__bf16)fmaxf(a2 + b2, 0.0f);
    r[3] = (__bf16)fmaxf(a3 + b3, 0.0f);
    *(bf16x4*)&p[(long)node * 256 + f0] = r;
}

// ---------------- bf16 MFMA GEMM: C[M,N] = A[M,K] * W[N,K]^T (+bias, act) ------
__device__ __forceinline__ void gl_lds16(const __bf16* g, __bf16* l) {
    __builtin_amdgcn_global_load_lds(
        (const __attribute__((address_space(1))) uint32_t*)g,
        (__attribute__((address_space(3))) uint32_t*)l, 16, 0, 0);
}

// ACT: 0 none, 1 leaky_relu(0.1), 2 relu. MCHK: row-bounds check in epilogue.
template <int ACT, bool BIAS, bool OUT_BF16, bool MCHK>
__global__ __launch_bounds__(256) void gemm_bt(
    const __bf16* __restrict__ A, int lda, const __bf16* __restrict__ W,
    const float* __restrict__ bias, void* __restrict__ Cout, int ldc,
    int K, int Mstore) {
    // LDS tile [128 rows][32 k], per-row XOR swizzle of the 8-elem k-group:
    // element (r,k) at r*32 + (((k>>3) ^ ((r>>1)&3))<<3) + (k&7)
    __shared__ __bf16 As[128 * 32];
    __shared__ __bf16 Ws[128 * 32];

    const int tid  = threadIdx.x;
    const int wid  = tid >> 6;
    const int lane = tid & 63;
    const long blockRow = (long)blockIdx.x * 128;
    const int  blockCol = blockIdx.y * 128;
    const int wm = (wid >> 1) << 6;
    const int wn = (wid & 1) << 6;

    f32x4 acc[4][4];
    #pragma unroll
    for (int i = 0; i < 4; ++i)
        #pragma unroll
        for (int j = 0; j < 4; ++j) acc[i][j] = (f32x4)0.0f;

    const int c0 = wid * 2;
    const int lr = lane >> 2;
    const int kg = (lane & 3) ^ ((lane >> 3) & 3);
    const __bf16* gA0 = A + (blockRow + c0 * 16 + lr) * (long)lda + kg * 8;
    const __bf16* gA1 = gA0 + 16L * lda;
    const __bf16* gW0 = W + ((long)blockCol + c0 * 16 + lr) * (long)K + kg * 8;
    const __bf16* gW1 = gW0 + 16L * K;
    __bf16* lA0 = As + c0 * 512;
    __bf16* lA1 = lA0 + 512;
    __bf16* lW0 = Ws + c0 * 512;
    __bf16* lW1 = lW0 + 512;

    const int rA  = lane & 15;
    const int q   = lane >> 4;
    const int swz = ((q ^ ((rA >> 1) & 3)) << 3);

    for (int k0 = 0; k0 < K; k0 += 32) {
        gl_lds16(gA0 + k0, lA0);
        gl_lds16(gA1 + k0, lA1);
        gl_lds16(gW0 + k0, lW0);
        gl_lds16(gW1 + k0, lW1);
        __syncthreads();

        bf16x8 af[4], bf[4];
        #pragma unroll
        for (int mi = 0; mi < 4; ++mi)
            af[mi] = *(const bf16x8*)&As[(wm + mi * 16 + rA) * 32 + swz];
        #pragma unroll
        for (int ni = 0; ni < 4; ++ni)
            bf[ni] = *(const bf16x8*)&Ws[(wn + ni * 16 + rA) * 32 + swz];
        #pragma unroll
        for (int mi = 0; mi < 4; ++mi)
            #pragma unroll
            for (int ni = 0; ni < 4; ++ni)
                acc[mi][ni] = __builtin_amdgcn_mfma_f32_16x16x32_bf16(
                    af[mi], bf[ni], acc[mi][ni], 0, 0, 0);
        __syncthreads();
    }

    // epilogue: C/D layout col=lane&15, row=(lane>>4)*4+reg
    const int ccol = lane & 15;
    const int crow = (lane >> 4) << 2;
    #pragma unroll
    for (int mi = 0; mi < 4; ++mi) {
        #pragma unroll
        for (int ni = 0; ni < 4; ++ni) {
            long gr0 = blockRow + wm + mi * 16 + crow;
            int  gc  = blockCol + wn + ni * 16 + ccol;
            float bv = BIAS ? bias[gc] : 0.0f;
            #pragma unroll
            for (int r = 0; r < 4; ++r) {
                long gr = gr0 + r;
                if (!MCHK || gr < Mstore) {
                    float v = acc[mi][ni][r] + bv;
                    if (ACT == 1) v = (v > 0.0f) ? v : 0.1f * v;
                    else if (ACT == 2) v = fmaxf(v, 0.0f);
                    if (OUT_BF16) ((__bf16*)Cout)[gr * ldc + gc] = (__bf16)v;
                    else          ((float*)Cout)[gr * ldc + gc] = v;
                }
            }
        }
    }
}

extern "C" void kernel_launch(void* const* d_in, const int* in_sizes, int n_in,
                              void* d_out, int out_size, void* d_ws, size_t ws_size,
                              hipStream_t stream) {
    const float* x    = (const float*)d_in[0];
    const int*   ei   = (const int*)d_in[1];
    const float* W_s1 = (const float*)d_in[2];
    const float* b_s1 = (const float*)d_in[3];
    const float* W_s2 = (const float*)d_in[4];
    const float* b_s2 = (const float*)d_in[5];
    const float* W_s3 = (const float*)d_in[6];
    const float* b_s3 = (const float*)d_in[7];
    const float* W_s4 = (const float*)d_in[8];
    const float* b_s4 = (const float*)d_in[9];
    const float* W_m1 = (const float*)d_in[10];
    const float* b_m1 = (const float*)d_in[11];
    const float* W_m2 = (const float*)d_in[12];
    const float* b_m2 = (const float*)d_in[13];
    const float* W_l1 = (const float*)d_in[14];
    const float* b_l1 = (const float*)d_in[15];
    const float* W_l2 = (const float*)d_in[16];
    const float* b_l2 = (const float*)d_in[17];

    char* ws = (char*)d_ws;
    size_t off = 0;
    auto carve = [&](size_t bytes) -> void* {
        void* p = ws + off;
        off = (off + bytes + 255) & ~(size_t)255;
        return p;
    };
    int* cnt  = (int*)carve((size_t)N_NODES * 4);
    int* cur  = (int*)carve((size_t)N_NODES * 4);
    int* ptr  = (int*)carve((size_t)(N_NODES + 1) * 4);
    int* col  = (int*)carve((size_t)E_EDGES * 4);
    int* bsum = (int*)carve(64 * 4);
    int* boff = (int*)carve(64 * 4);
    __bf16* wbuf = (__bf16*)carve((size_t)WTOT * 2);
    __bf16* w1  = wbuf;
    __bf16* w2  = wbuf +  32768;
    __bf16* w3  = wbuf + 294912;
    __bf16* w4  = wbuf + 557056;
    __bf16* wml = wbuf + 819200;   // [W_m1 ; W_l1] rows, 256x512
    __bf16* wm2 = wbuf + 950272;
    __bf16* wl2 = wbuf + 966656;
    __bf16* xb    = (__bf16*)carve((size_t)XN * 2);
    __bf16* agg0b = (__bf16*)carve((size_t)N_PAD * 64 * 2);
    __bf16* B1    = (__bf16*)carve((size_t)N_PAD * 512 * 2);
    __bf16* B2    = (__bf16*)carve((size_t)N_PAD * 512 * 2);

    (void)hipMemsetAsync(cnt, 0, (size_t)N_NODES * 4, stream);
    (void)hipMemsetAsync(cur, 0, (size_t)N_NODES * 4, stream);

    // CSR build
    const int NB = (N_NODES + SCAN_B - 1) / SCAN_B;  // 49
    count_deg<<<E_EDGES / 256, 256, 0, stream>>>(ei, cnt);
    scan_block<<<NB, SCAN_B, 0, stream>>>(cnt, ptr, bsum, N_NODES);
    scan_bsums<<<1, 64, 0, stream>>>(bsum, boff, NB, &ptr[N_NODES]);
    scan_add<<<NB, SCAN_B, 0, stream>>>(ptr, boff, N_NODES);
    fill_csr<<<E_EDGES / 256, 256, 0, stream>>>(ei, ptr, cur, col);

    // one-shot conversions (x + all 8 weight matrices)
    cvt_all<<<(XN + WTOT + 255) / 256, 256, 0, stream>>>(
        x, W_s1, W_s2, W_s3, W_s4, W_m1, W_l1, W_m2, W_l2, xb, wbuf);

    // first aggregation (bf16 gather, fp32 accumulate)
    agg0_gather<<<N_PAD / 4, 256, 0, stream>>>(xb, ptr, col, agg0b);

    // shared MLP: 64->512->512->512->512, lrelu x3, final +b then relu
    gemm_bt<1, true, true, false><<<dim3(MT, 4), 256, 0, stream>>>(agg0b, 64, w1, b_s1, B1, 512, 64, N_PAD);
    gemm_bt<1, true, true, false><<<dim3(MT, 4), 256, 0, stream>>>(B1, 512, w2, b_s2, B2, 512, 512, N_PAD);
    gemm_bt<1, true, true, false><<<dim3(MT, 4), 256, 0, stream>>>(B2, 512, w3, b_s3, B1, 512, 512, N_PAD);
    gemm_bt<2, true, true, false><<<dim3(MT, 4), 256, 0, stream>>>(B1, 512, w4, b_s4, B2, 512, 512, N_PAD);

    // project h -> 256 (mu|logvar heads) BEFORE aggregation; bf16 output
    __bf16* t = B1;  // N_PAD x 256 bf16 (first half of B1's bytes)
    gemm_bt<0, false, true, false><<<dim3(MT, 2), 256, 0, stream>>>(B2, 512, wml, nullptr, t, 256, 512, N_PAD);

    // second aggregation on 256-dim bf16 rows, fused bias+relu
    __bf16* p = B2;  // N x 256 bf16
    aggt_gather<<<(N_NODES + 3) / 4, 256, 0, stream>>>(t, ptr, col, b_m1, b_l1, p);

    // heads
    float* mu = (float*)d_out;
    float* lv = mu + (size_t)N_NODES * 128;
    gemm_bt<0, true, false, true><<<dim3(MT, 1), 256, 0, stream>>>(p, 256, wm2, b_m2, mu, 128, 128, N_NODES);
    gemm_bt<0, true, false, true><<<dim3(MT, 1), 256, 0, stream>>>(p + 128, 256, wl2, b_l2, lv, 128, 128, N_NODES);
}